// Round 1
// baseline (721.658 us; speedup 1.0000x reference)
//
#include <hip/hip_runtime.h>
#include <math.h>

#define SELU_LAMBDA 1.0507009873554805f
#define SELU_ALPHA  1.6732632423543772f

// ---------------------------------------------------------------- CSR build
__global__ __launch_bounds__(256) void k_count_deg(const int* __restrict__ dst,
                                                   int* __restrict__ deg, int e) {
  int i = blockIdx.x * 256 + threadIdx.x;
  if (i < e) atomicAdd(&deg[dst[i]], 1);
}

// single-block exclusive scan over n ints (n up to a few hundred K)
__global__ __launch_bounds__(1024) void k_scan(const int* __restrict__ deg,
                                               int* __restrict__ offs, int n) {
  __shared__ int wsum[16];
  __shared__ int carry;
  const int tid = threadIdx.x;
  const int lane = tid & 63;
  const int w = tid >> 6;
  if (tid == 0) carry = 0;
  __syncthreads();
  for (int base = 0; base < n; base += 1024) {
    int i = base + tid;
    int v = (i < n) ? deg[i] : 0;
    int s = v;
#pragma unroll
    for (int d = 1; d < 64; d <<= 1) {
      int t = __shfl_up(s, d, 64);
      if (lane >= d) s += t;
    }
    if (lane == 63) wsum[w] = s;
    __syncthreads();
    if (w == 0) {
      int t = (lane < 16) ? wsum[lane] : 0;
#pragma unroll
      for (int d = 1; d < 16; d <<= 1) {
        int u = __shfl_up(t, d, 64);
        if (lane >= d) t += u;
      }
      if (lane < 16) wsum[lane] = t;
    }
    __syncthreads();
    int cbase = carry;
    int wbase = (w == 0) ? 0 : wsum[w - 1];
    if (i < n) offs[i] = cbase + wbase + s - v;  // exclusive
    __syncthreads();
    if (tid == 0) carry = cbase + wsum[15];
    __syncthreads();
  }
  if (tid == 0) offs[n] = carry;
}

__global__ __launch_bounds__(256) void k_fill_csr(const int* __restrict__ src,
    const int* __restrict__ dst, int* __restrict__ cursor,
    int* __restrict__ csr, int e) {
  int i = blockIdx.x * 256 + threadIdx.x;
  if (i < e) {
    int p = atomicAdd(&cursor[dst[i]], 1);
    csr[p] = src[i];
  }
}

// ---------------------------------------------------------------- hops
// one wave per node; lane owns 2 consecutive dims (float2 -> 512B per row)
__global__ __launch_bounds__(256) void k_hop128(const float2* __restrict__ hin,
    float2* __restrict__ hout, const int* __restrict__ offs,
    const int* __restrict__ csr, int n) {
  int wid = (blockIdx.x * 256 + threadIdx.x) >> 6;
  if (wid >= n) return;
  int lane = threadIdx.x & 63;
  int beg = offs[wid], end = offs[wid + 1];
  size_t base = (size_t)wid * 64 + lane;
  float2 acc = hin[base];                // self term (unit diagonal)
  int e = beg;
  for (; e + 1 < end; e += 2) {
    int j0 = csr[e], j1 = csr[e + 1];
    float2 v0 = hin[(size_t)j0 * 64 + lane];
    float2 v1 = hin[(size_t)j1 * 64 + lane];
    acc.x += v0.x + v1.x;
    acc.y += v0.y + v1.y;
  }
  if (e < end) {
    float2 v = hin[(size_t)csr[e] * 64 + lane];
    acc.x += v.x;
    acc.y += v.y;
  }
  hout[base] = acc;
}

// one wave per node; lane owns 1 dim (D = 64)
__global__ __launch_bounds__(256) void k_hop64(const float* __restrict__ hin,
    float* __restrict__ hout, const int* __restrict__ offs,
    const int* __restrict__ csr, int n) {
  int wid = (blockIdx.x * 256 + threadIdx.x) >> 6;
  if (wid >= n) return;
  int lane = threadIdx.x & 63;
  int beg = offs[wid], end = offs[wid + 1];
  size_t base = (size_t)wid * 64 + lane;
  float acc = hin[base];
  int e = beg;
  for (; e + 1 < end; e += 2) {
    int j0 = csr[e], j1 = csr[e + 1];
    acc += hin[(size_t)j0 * 64 + lane] + hin[(size_t)j1 * 64 + lane];
  }
  if (e < end) acc += hin[(size_t)csr[e] * 64 + lane];
  hout[base] = acc;
}

// ---------------------------------------------------------------- GEMM1 (+bias) fused with batch stats
// block: 256 threads, 64 rows x 64 cols; thread = 4 rows x 4 cols
__global__ __launch_bounds__(256) void k_gemm1_stats(
    const float* __restrict__ A,   // N x 128
    const float* __restrict__ W1,  // 128 x 64
    const float* __restrict__ b1,  // 64
    float* __restrict__ H,         // N x 64
    float* __restrict__ stats,     // [0:64) sum, [64:128) sumsq
    int n) {
  __shared__ float Ws[128 * 64];
  for (int t = threadIdx.x; t < 128 * 64; t += 256) Ws[t] = W1[t];
  __syncthreads();

  const int rg = threadIdx.x >> 4;        // 0..15 (row group)
  const int c0 = (threadIdx.x & 15) * 4;  // 0..60
  const int row0 = blockIdx.x * 64 + rg * 4;

  float acc[4][4] = {};
  for (int k = 0; k < 128; k += 4) {
    float4 a[4];
#pragma unroll
    for (int r = 0; r < 4; ++r) {
      int row = row0 + r;
      int rowc = row < n ? row : n - 1;   // clamp; OOB rows masked at store
      a[r] = *(const float4*)&A[(size_t)rowc * 128 + k];
    }
    float4 w0 = *(const float4*)&Ws[(k + 0) * 64 + c0];
    float4 w1 = *(const float4*)&Ws[(k + 1) * 64 + c0];
    float4 w2 = *(const float4*)&Ws[(k + 2) * 64 + c0];
    float4 w3 = *(const float4*)&Ws[(k + 3) * 64 + c0];
#pragma unroll
    for (int r = 0; r < 4; ++r) {
      acc[r][0] += a[r].x * w0.x + a[r].y * w1.x + a[r].z * w2.x + a[r].w * w3.x;
      acc[r][1] += a[r].x * w0.y + a[r].y * w1.y + a[r].z * w2.y + a[r].w * w3.y;
      acc[r][2] += a[r].x * w0.z + a[r].y * w1.z + a[r].z * w2.z + a[r].w * w3.z;
      acc[r][3] += a[r].x * w0.w + a[r].y * w1.w + a[r].z * w2.w + a[r].w * w3.w;
    }
  }

  float4 bv = *(const float4*)&b1[c0];
  __shared__ float ps1[16][64];
  __shared__ float ps2[16][64];
  float s1[4] = {}, s2[4] = {};
#pragma unroll
  for (int r = 0; r < 4; ++r) {
    int row = row0 + r;
    if (row < n) {
      float4 v;
      v.x = acc[r][0] + bv.x;
      v.y = acc[r][1] + bv.y;
      v.z = acc[r][2] + bv.z;
      v.w = acc[r][3] + bv.w;
      *(float4*)&H[(size_t)row * 64 + c0] = v;
      s1[0] += v.x; s1[1] += v.y; s1[2] += v.z; s1[3] += v.w;
      s2[0] += v.x * v.x; s2[1] += v.y * v.y; s2[2] += v.z * v.z; s2[3] += v.w * v.w;
    }
  }
  *(float4*)&ps1[rg][c0] = make_float4(s1[0], s1[1], s1[2], s1[3]);
  *(float4*)&ps2[rg][c0] = make_float4(s2[0], s2[1], s2[2], s2[3]);
  __syncthreads();
  if (threadIdx.x < 64) {
    float t1 = 0.f, t2 = 0.f;
#pragma unroll
    for (int j = 0; j < 16; ++j) {
      t1 += ps1[j][threadIdx.x];
      t2 += ps2[j][threadIdx.x];
    }
    atomicAdd(&stats[threadIdx.x], t1);
    atomicAdd(&stats[64 + threadIdx.x], t2);
  }
}

__global__ void k_finalize_stats(const float* __restrict__ stats,
    const float* __restrict__ bn_w, const float* __restrict__ bn_b,
    float* __restrict__ ab, int n) {
  int f = threadIdx.x;
  if (f < 64) {
    float inv_n = 1.0f / (float)n;
    float mu = stats[f] * inv_n;
    float var = stats[64 + f] * inv_n - mu * mu;
    float s = bn_w[f] * rsqrtf(var + 1e-5f);
    ab[f] = s;
    ab[64 + f] = bn_b[f] - mu * s;
  }
}

__global__ __launch_bounds__(256) void k_bn_selu(float* __restrict__ H,
    const float* __restrict__ ab, int n4) {  // n4 = N*64/4
  int i = blockIdx.x * 256 + threadIdx.x;
  if (i >= n4) return;
  float4 v = ((float4*)H)[i];
  int c = (i << 2) & 63;
  float4 s = *(const float4*)&ab[c];
  float4 sh = *(const float4*)&ab[64 + c];
  float y;
  y = s.x * v.x + sh.x; v.x = y > 0.f ? SELU_LAMBDA * y : SELU_LAMBDA * SELU_ALPHA * expm1f(y);
  y = s.y * v.y + sh.y; v.y = y > 0.f ? SELU_LAMBDA * y : SELU_LAMBDA * SELU_ALPHA * expm1f(y);
  y = s.z * v.z + sh.z; v.z = y > 0.f ? SELU_LAMBDA * y : SELU_LAMBDA * SELU_ALPHA * expm1f(y);
  y = s.w * v.w + sh.w; v.w = y > 0.f ? SELU_LAMBDA * y : SELU_LAMBDA * SELU_ALPHA * expm1f(y);
  ((float4*)H)[i] = v;
}

// ---------------------------------------------------------------- final GEMM + log_softmax
// one thread per row; W2/b2 read via wave-uniform loads (scalarized)
__global__ __launch_bounds__(256) void k_final(const float* __restrict__ A,  // N x 64
    const float* __restrict__ W2,  // 64 x 16
    const float* __restrict__ b2,  // 16
    float* __restrict__ out, int n) {
  int row = blockIdx.x * 256 + threadIdx.x;
  if (row >= n) return;
  float4 acc[4];
  acc[0] = *(const float4*)&b2[0];
  acc[1] = *(const float4*)&b2[4];
  acc[2] = *(const float4*)&b2[8];
  acc[3] = *(const float4*)&b2[12];
  const float4* A4 = (const float4*)(A + (size_t)row * 64);
#pragma unroll
  for (int k = 0; k < 64; k += 4) {
    float4 a = A4[k >> 2];
#pragma unroll
    for (int kk = 0; kk < 4; ++kk) {
      float ak = kk == 0 ? a.x : kk == 1 ? a.y : kk == 2 ? a.z : a.w;
      const float4* Wr = (const float4*)&W2[(k + kk) * 16];
      float4 w0 = Wr[0], w1 = Wr[1], w2 = Wr[2], w3 = Wr[3];
      acc[0].x += ak * w0.x; acc[0].y += ak * w0.y; acc[0].z += ak * w0.z; acc[0].w += ak * w0.w;
      acc[1].x += ak * w1.x; acc[1].y += ak * w1.y; acc[1].z += ak * w1.z; acc[1].w += ak * w1.w;
      acc[2].x += ak * w2.x; acc[2].y += ak * w2.y; acc[2].z += ak * w2.z; acc[2].w += ak * w2.w;
      acc[3].x += ak * w3.x; acc[3].y += ak * w3.y; acc[3].z += ak * w3.z; acc[3].w += ak * w3.w;
    }
  }
  // log_softmax over the 16 values
  float m = acc[0].x;
#pragma unroll
  for (int q = 0; q < 4; ++q) {
    m = fmaxf(m, acc[q].x); m = fmaxf(m, acc[q].y);
    m = fmaxf(m, acc[q].z); m = fmaxf(m, acc[q].w);
  }
  float ssum = 0.f;
#pragma unroll
  for (int q = 0; q < 4; ++q) {
    ssum += expf(acc[q].x - m) + expf(acc[q].y - m) +
            expf(acc[q].z - m) + expf(acc[q].w - m);
  }
  float ls = m + logf(ssum);
#pragma unroll
  for (int q = 0; q < 4; ++q) {
    acc[q].x -= ls; acc[q].y -= ls; acc[q].z -= ls; acc[q].w -= ls;
  }
  float4* o = (float4*)(out + (size_t)row * 16);
  o[0] = acc[0]; o[1] = acc[1]; o[2] = acc[2]; o[3] = acc[3];
}

// ---------------------------------------------------------------- launch
extern "C" void kernel_launch(void* const* d_in, const int* in_sizes, int n_in,
                              void* d_out, int out_size, void* d_ws, size_t ws_size,
                              hipStream_t stream) {
  const float* x   = (const float*)d_in[0];
  const int* esrc  = (const int*)d_in[1];
  const int* edst  = (const int*)d_in[2];
  const float* W1  = (const float*)d_in[3];
  const float* b1  = (const float*)d_in[4];
  const float* bnw = (const float*)d_in[5];
  const float* bnb = (const float*)d_in[6];
  const float* W2  = (const float*)d_in[7];
  const float* b2  = (const float*)d_in[8];
  float* out = (float*)d_out;

  const int N = in_sizes[0] / 128;  // 100000
  const int E = in_sizes[1];        // 1600000

  char* p = (char*)d_ws;
  auto alloc = [&](size_t bytes) {
    char* q = p;
    p += (bytes + 255) & ~(size_t)255;
    return q;
  };
  int* offs    = (int*)alloc((size_t)(N + 1) * sizeof(int));
  int* deg     = (int*)alloc((size_t)N * sizeof(int));
  int* cursor  = (int*)alloc((size_t)N * sizeof(int));
  int* csr     = (int*)alloc((size_t)E * sizeof(int));
  float* stats = (float*)alloc(128 * sizeof(float));
  float* ab    = (float*)alloc(128 * sizeof(float));
  float* bufA  = (float*)alloc((size_t)N * 128 * sizeof(float));
  float* bufB  = (float*)alloc((size_t)N * 128 * sizeof(float));
  float* bufC  = (float*)alloc((size_t)N * 64 * sizeof(float));

  hipMemsetAsync(deg, 0, (size_t)N * sizeof(int), stream);
  hipMemsetAsync(stats, 0, 128 * sizeof(float), stream);

  k_count_deg<<<(E + 255) / 256, 256, 0, stream>>>(edst, deg, E);
  k_scan<<<1, 1024, 0, stream>>>(deg, offs, N);
  hipMemcpyAsync(cursor, offs, (size_t)N * sizeof(int),
                 hipMemcpyDeviceToDevice, stream);
  k_fill_csr<<<(E + 255) / 256, 256, 0, stream>>>(esrc, edst, cursor, csr, E);

  int hopBlocks = (N * 64 + 255) / 256;  // one wave per node
  k_hop128<<<hopBlocks, 256, 0, stream>>>((const float2*)x, (float2*)bufA, offs, csr, N);
  k_hop128<<<hopBlocks, 256, 0, stream>>>((const float2*)bufA, (float2*)bufB, offs, csr, N);

  k_gemm1_stats<<<(N + 63) / 64, 256, 0, stream>>>(bufB, W1, b1, bufC, stats, N);
  k_finalize_stats<<<1, 64, 0, stream>>>(stats, bnw, bnb, ab, N);
  k_bn_selu<<<(N * 16 + 255) / 256, 256, 0, stream>>>(bufC, ab, N * 16);

  k_hop64<<<hopBlocks, 256, 0, stream>>>(bufC, bufA, offs, csr, N);
  k_final<<<(N + 255) / 256, 256, 0, stream>>>(bufA, W2, b2, out, N);
}

// Round 2
// 558.714 us; speedup vs baseline: 1.2916x; 1.2916x over previous
//
#include <hip/hip_runtime.h>
#include <math.h>

#define SELU_LAMBDA 1.0507009873554805f
#define SELU_ALPHA  1.6732632423543772f

// ---------------------------------------------------------------- CSR build
__global__ __launch_bounds__(256) void k_count_deg(const int* __restrict__ dst,
                                                   int* __restrict__ deg, int e) {
  int i = blockIdx.x * 256 + threadIdx.x;
  if (i < e) atomicAdd(&deg[dst[i]], 1);
}

// single-block exclusive scan, 4 elements/thread; writes offs AND cursor
__global__ __launch_bounds__(1024) void k_scan4(const int* __restrict__ deg,
                                                int* __restrict__ offs,
                                                int* __restrict__ cursor, int n) {
  __shared__ int wsum[16];
  __shared__ int carry;
  const int tid = threadIdx.x;
  const int lane = tid & 63;
  const int w = tid >> 6;
  if (tid == 0) carry = 0;
  __syncthreads();
  const int n4 = (n + 3) >> 2;
  for (int base = 0; base < n4; base += 1024) {
    int i = base + tid;
    int4 v = make_int4(0, 0, 0, 0);
    if (i < n4) v = ((const int4*)deg)[i];
    int t = v.x + v.y + v.z + v.w;
    int s = t;
#pragma unroll
    for (int d = 1; d < 64; d <<= 1) {
      int u = __shfl_up(s, d, 64);
      if (lane >= d) s += u;
    }
    if (lane == 63) wsum[w] = s;
    __syncthreads();
    if (w == 0) {
      int t2 = (lane < 16) ? wsum[lane] : 0;
#pragma unroll
      for (int d = 1; d < 16; d <<= 1) {
        int u = __shfl_up(t2, d, 64);
        if (lane >= d) t2 += u;
      }
      if (lane < 16) wsum[lane] = t2;
    }
    __syncthreads();
    int cbase = carry;
    int wbase = (w == 0) ? 0 : wsum[w - 1];
    if (i < n4) {
      int e0 = cbase + wbase + s - t;  // exclusive prefix of element 4i
      int4 o;
      o.x = e0;
      o.y = e0 + v.x;
      o.z = o.y + v.y;
      o.w = o.z + v.z;
      ((int4*)offs)[i] = o;
      ((int4*)cursor)[i] = o;
    }
    __syncthreads();
    if (tid == 0) carry = cbase + wsum[15];
    __syncthreads();
  }
  if (tid == 0) offs[n] = carry;
}

__global__ __launch_bounds__(256) void k_fill_csr(const int* __restrict__ src,
    const int* __restrict__ dst, int* __restrict__ cursor,
    int* __restrict__ csr, int e) {
  int i = blockIdx.x * 256 + threadIdx.x;
  if (i < e) {
    int p = atomicAdd(&cursor[dst[i]], 1);
    csr[p] = src[i];
  }
}

// ---------------------------------------------------------------- GEMM1: X(Nx128) @ W1(128x64) -> H(Nx64), no bias
// block: 256 threads, 64 rows x 64 cols; thread = 4 rows x 4 cols
__global__ __launch_bounds__(256) void k_gemm1(
    const float* __restrict__ A, const float* __restrict__ W1,
    float* __restrict__ H, int n) {
  __shared__ float Ws[128 * 64];
  for (int t = threadIdx.x; t < 128 * 64; t += 256) Ws[t] = W1[t];
  __syncthreads();

  const int rg = threadIdx.x >> 4;
  const int c0 = (threadIdx.x & 15) * 4;
  const int row0 = blockIdx.x * 64 + rg * 4;

  float acc[4][4] = {};
  for (int k = 0; k < 128; k += 4) {
    float4 a[4];
#pragma unroll
    for (int r = 0; r < 4; ++r) {
      int row = row0 + r;
      int rowc = row < n ? row : n - 1;
      a[r] = *(const float4*)&A[(size_t)rowc * 128 + k];
    }
    float4 w0 = *(const float4*)&Ws[(k + 0) * 64 + c0];
    float4 w1 = *(const float4*)&Ws[(k + 1) * 64 + c0];
    float4 w2 = *(const float4*)&Ws[(k + 2) * 64 + c0];
    float4 w3 = *(const float4*)&Ws[(k + 3) * 64 + c0];
#pragma unroll
    for (int r = 0; r < 4; ++r) {
      acc[r][0] += a[r].x * w0.x + a[r].y * w1.x + a[r].z * w2.x + a[r].w * w3.x;
      acc[r][1] += a[r].x * w0.y + a[r].y * w1.y + a[r].z * w2.y + a[r].w * w3.y;
      acc[r][2] += a[r].x * w0.z + a[r].y * w1.z + a[r].z * w2.z + a[r].w * w3.z;
      acc[r][3] += a[r].x * w0.w + a[r].y * w1.w + a[r].z * w2.w + a[r].w * w3.w;
    }
  }
#pragma unroll
  for (int r = 0; r < 4; ++r) {
    int row = row0 + r;
    if (row < n) {
      *(float4*)&H[(size_t)row * 64 + c0] =
          make_float4(acc[r][0], acc[r][1], acc[r][2], acc[r][3]);
    }
  }
}

// ---------------------------------------------------------------- hop at D=64: one wave per node
__global__ __launch_bounds__(256) void k_hop64(const float* __restrict__ hin,
    float* __restrict__ hout, const int* __restrict__ offs,
    const int* __restrict__ csr, int n) {
  int wid = (blockIdx.x * 256 + threadIdx.x) >> 6;
  if (wid >= n) return;
  int lane = threadIdx.x & 63;
  int beg = offs[wid], end = offs[wid + 1];
  size_t base = (size_t)wid * 64 + lane;
  float acc = hin[base];
  int e = beg;
  for (; e + 1 < end; e += 2) {
    int j0 = csr[e], j1 = csr[e + 1];
    acc += hin[(size_t)j0 * 64 + lane] + hin[(size_t)j1 * 64 + lane];
  }
  if (e < end) acc += hin[(size_t)csr[e] * 64 + lane];
  hout[base] = acc;
}

// ---------------------------------------------------------------- batch stats (sum, sumsq per column)
__global__ __launch_bounds__(256) void k_stats(const float* __restrict__ H,
    float* __restrict__ stats, int n) {
  const int col = threadIdx.x & 63;
  const int rg = threadIdx.x >> 6;  // 0..3
  float s1 = 0.f, s2 = 0.f;
  for (int row = blockIdx.x * 4 + rg; row < n; row += gridDim.x * 4) {
    float v = H[(size_t)row * 64 + col];
    s1 += v;
    s2 += v * v;
  }
  __shared__ float l1[4][64];
  __shared__ float l2[4][64];
  l1[rg][col] = s1;
  l2[rg][col] = s2;
  __syncthreads();
  if (threadIdx.x < 64) {
    float t1 = l1[0][col] + l1[1][col] + l1[2][col] + l1[3][col];
    float t2 = l2[0][col] + l2[1][col] + l2[2][col] + l2[3][col];
    atomicAdd(&stats[col], t1);
    atomicAdd(&stats[64 + col], t2);
  }
}

__global__ void k_finalize_stats(const float* __restrict__ stats,
    const float* __restrict__ bn_w, const float* __restrict__ bn_b,
    float* __restrict__ ab, int n) {
  int f = threadIdx.x;
  if (f < 64) {
    float inv_n = 1.0f / (float)n;
    float mu = stats[f] * inv_n;
    float var = stats[64 + f] * inv_n - mu * mu;
    float s = bn_w[f] * rsqrtf(var + 1e-5f);
    ab[f] = s;
    ab[64 + f] = bn_b[f] - mu * s;
  }
}

// ---------------------------------------------------------------- GEMM2 with fused BN affine + SELU
// one thread per row: y[row,:] = selu(ab*h+sh) @ W2   (no bias here)
__global__ __launch_bounds__(256) void k_gemm2(const float* __restrict__ A,
    const float* __restrict__ ab, const float* __restrict__ W2,
    float* __restrict__ Y, int n) {
  int row = blockIdx.x * 256 + threadIdx.x;
  if (row >= n) return;
  float4 acc[4] = {make_float4(0, 0, 0, 0), make_float4(0, 0, 0, 0),
                   make_float4(0, 0, 0, 0), make_float4(0, 0, 0, 0)};
  const float4* A4 = (const float4*)(A + (size_t)row * 64);
#pragma unroll
  for (int k = 0; k < 64; k += 4) {
    float4 a = A4[k >> 2];
    float av[4] = {a.x, a.y, a.z, a.w};
#pragma unroll
    for (int kk = 0; kk < 4; ++kk) {
      float y = ab[k + kk] * av[kk] + ab[64 + k + kk];
      y = y > 0.f ? SELU_LAMBDA * y : SELU_LAMBDA * SELU_ALPHA * expm1f(y);
      const float4* Wr = (const float4*)&W2[(k + kk) * 16];
      float4 w0 = Wr[0], w1 = Wr[1], w2 = Wr[2], w3 = Wr[3];
      acc[0].x += y * w0.x; acc[0].y += y * w0.y; acc[0].z += y * w0.z; acc[0].w += y * w0.w;
      acc[1].x += y * w1.x; acc[1].y += y * w1.y; acc[1].z += y * w1.z; acc[1].w += y * w1.w;
      acc[2].x += y * w2.x; acc[2].y += y * w2.y; acc[2].z += y * w2.z; acc[2].w += y * w2.w;
      acc[3].x += y * w3.x; acc[3].y += y * w3.y; acc[3].z += y * w3.z; acc[3].w += y * w3.w;
    }
  }
  float4* o = (float4*)(Y + (size_t)row * 16);
  o[0] = acc[0]; o[1] = acc[1]; o[2] = acc[2]; o[3] = acc[3];
}

// ---------------------------------------------------------------- hop at D=16 + b2 + log_softmax
// one wave per node: 4 sub-groups of 16 lanes each handle one edge in parallel
__global__ __launch_bounds__(256) void k_hop16(const float* __restrict__ Y,
    const float* __restrict__ b2, float* __restrict__ out,
    const int* __restrict__ offs, const int* __restrict__ csr, int n) {
  int wid = (blockIdx.x * 256 + threadIdx.x) >> 6;
  if (wid >= n) return;
  int lane = threadIdx.x & 63;
  int sub = lane >> 4, dim = lane & 15;
  int beg = offs[wid], end = offs[wid + 1];
  float acc = 0.f;
  for (int e = beg; e < end; e += 8) {
    int i0 = e + sub, i1 = e + 4 + sub;
    float v0 = 0.f, v1 = 0.f;
    if (i0 < end) v0 = Y[(size_t)csr[i0] * 16 + dim];
    if (i1 < end) v1 = Y[(size_t)csr[i1] * 16 + dim];
    acc += v0 + v1;
  }
  acc += __shfl_down(acc, 32, 64);
  acc += __shfl_down(acc, 16, 64);
  // lanes 0..15: total neighbor sum; add self + b2
  float v = acc + Y[(size_t)wid * 16 + dim] + b2[dim];
  float m = v;
#pragma unroll
  for (int d = 8; d >= 1; d >>= 1) m = fmaxf(m, __shfl_xor(m, d, 16));
  float s = expf(v - m);
#pragma unroll
  for (int d = 8; d >= 1; d >>= 1) s += __shfl_xor(s, d, 16);
  float r = v - (m + logf(s));
  if (lane < 16) out[(size_t)wid * 16 + dim] = r;
}

// ---------------------------------------------------------------- launch
extern "C" void kernel_launch(void* const* d_in, const int* in_sizes, int n_in,
                              void* d_out, int out_size, void* d_ws, size_t ws_size,
                              hipStream_t stream) {
  const float* x   = (const float*)d_in[0];
  const int* esrc  = (const int*)d_in[1];
  const int* edst  = (const int*)d_in[2];
  const float* W1  = (const float*)d_in[3];
  // d_in[4] = b1: cancels exactly under batchnorm mean subtraction
  const float* bnw = (const float*)d_in[5];
  const float* bnb = (const float*)d_in[6];
  const float* W2  = (const float*)d_in[7];
  const float* b2  = (const float*)d_in[8];
  float* out = (float*)d_out;

  const int N = in_sizes[0] / 128;  // 100000
  const int E = in_sizes[1];        // 1600000

  char* p = (char*)d_ws;
  auto alloc = [&](size_t bytes) {
    char* q = p;
    p += (bytes + 255) & ~(size_t)255;
    return q;
  };
  int* offs    = (int*)alloc((size_t)(N + 4) * sizeof(int));
  int* deg     = (int*)alloc((size_t)(N + 4) * sizeof(int));
  int* cursor  = (int*)alloc((size_t)(N + 4) * sizeof(int));
  int* csr     = (int*)alloc((size_t)E * sizeof(int));
  float* stats = (float*)alloc(128 * sizeof(float));
  float* ab    = (float*)alloc(128 * sizeof(float));
  float* bufA  = (float*)alloc((size_t)N * 64 * sizeof(float));
  float* bufB  = (float*)alloc((size_t)N * 64 * sizeof(float));
  float* bufC  = (float*)alloc((size_t)N * 16 * sizeof(float));

  hipMemsetAsync(deg, 0, (size_t)(N + 4) * sizeof(int), stream);
  hipMemsetAsync(stats, 0, 128 * sizeof(float), stream);

  k_count_deg<<<(E + 255) / 256, 256, 0, stream>>>(edst, deg, E);
  k_scan4<<<1, 1024, 0, stream>>>(deg, offs, cursor, N);
  k_fill_csr<<<(E + 255) / 256, 256, 0, stream>>>(esrc, edst, cursor, csr, E);

  // GEMM first (propagation commutes with the linear layer): hops run at D=64
  k_gemm1<<<(N + 63) / 64, 256, 0, stream>>>(x, W1, bufA, N);

  int hopBlocks = (N * 64 + 255) / 256;  // one wave per node
  k_hop64<<<hopBlocks, 256, 0, stream>>>(bufA, bufB, offs, csr, N);
  k_hop64<<<hopBlocks, 256, 0, stream>>>(bufB, bufA, offs, csr, N);

  k_stats<<<512, 256, 0, stream>>>(bufA, stats, N);
  k_finalize_stats<<<1, 64, 0, stream>>>(stats, bnw, bnb, ab, N);

  // GEMM2 (with fused BN+SELU) before the last hop: hop runs at D=16
  k_gemm2<<<(N + 255) / 256, 256, 0, stream>>>(bufA, ab, W2, bufC, N);
  k_hop16<<<hopBlocks, 256, 0, stream>>>(bufC, b2, out, offs, csr, N);
}